// Round 1
// baseline (54.278 us; speedup 1.0000x reference)
//
#include <hip/hip_runtime.h>

// KGather: out[n,p,t,:,:] = r_weight[n,p,t] * k[n, r_idx[n,p,t], :, :]
// Shapes: r_idx (16,49,8) int, r_weight (16,49,8) f32, k (16,49,64,128) f32
// out (16,49,8,64,128) f32.  Pure memory-bound gather+scale.

constexpr int N    = 16;
constexpr int P2   = 49;
constexpr int TOPK = 8;
constexpr int W2   = 64;
constexpr int CK   = 128;
constexpr int WIN  = W2 * CK;      // 8192 floats = 32 KB per window
constexpr int WINV = WIN / 4;      // 2048 float4 per window

__global__ __launch_bounds__(256) void kgather_kernel(
    const int*   __restrict__ r_idx,
    const float* __restrict__ r_weight,
    const float* __restrict__ k,
    float*       __restrict__ out)
{
    const int b  = blockIdx.x;           // flat (n*P2 + p)*TOPK + t
    const int np = b / TOPK;             // n*P2 + p
    const int n  = np / P2;

    const int   idx = r_idx[b];          // routed region index in [0, P2)
    const float w   = r_weight[b];

    const float4* __restrict__ src =
        reinterpret_cast<const float4*>(k + (size_t)(n * P2 + idx) * WIN);
    float4* __restrict__ dst =
        reinterpret_cast<float4*>(out + (size_t)b * WIN);

    #pragma unroll
    for (int i = threadIdx.x; i < WINV; i += 256) {
        float4 v = src[i];
        v.x *= w; v.y *= w; v.z *= w; v.w *= w;
        dst[i] = v;
    }
}

extern "C" void kernel_launch(void* const* d_in, const int* in_sizes, int n_in,
                              void* d_out, int out_size, void* d_ws, size_t ws_size,
                              hipStream_t stream) {
    const int*   r_idx    = (const int*)  d_in[0];
    const float* r_weight = (const float*)d_in[1];
    const float* k        = (const float*)d_in[2];
    float*       out      = (float*)d_out;

    const int nwin = N * P2 * TOPK;      // 6272 windows
    kgather_kernel<<<nwin, 256, 0, stream>>>(r_idx, r_weight, k, out);
}

// Round 3
// 40.002 us; speedup vs baseline: 1.3569x; 1.3569x over previous
//
#include <hip/hip_runtime.h>

// KGather: out[n,p,t,:,:] = r_weight[n,p,t] * k[n, r_idx[n,p,t], :, :]
// Shapes: r_idx (16,49,8) int, r_weight (16,49,8) f32, k (16,49,64,128) f32
// out (16,49,8,64,128) f32.  Pure memory-bound gather+scale.
//
// Round 3: same as round 2 but with clang ext_vector float4 so
// __builtin_nontemporal_store compiles (HIP_vector_type is a struct and
// is rejected by the builtin).
//  (a) non-temporal stores: the 205 MB output stream doesn't allocate in /
//      evict k (25.7 MB, x8 logical reuse) from L2.
//  (b) XCD-chunked blockIdx swizzle: each XCD's 4 MiB L2 sees only its own
//      n-slabs (active read set ~3.2 MB per n), instead of all 25.7 MB.

typedef float f32x4 __attribute__((ext_vector_type(4)));

constexpr int N    = 16;
constexpr int P2   = 49;
constexpr int TOPK = 8;
constexpr int W2   = 64;
constexpr int CK   = 128;
constexpr int WIN  = W2 * CK;      // 8192 floats = 32 KB per window
constexpr int WINV = WIN / 4;      // 2048 float4 per window
constexpr int NXCD = 8;
constexpr int NWG  = N * P2 * TOPK;        // 6272, divisible by 8
constexpr int CPX  = NWG / NXCD;           // 784 blocks per XCD chunk

__global__ __launch_bounds__(256) void kgather_kernel(
    const int*   __restrict__ r_idx,
    const float* __restrict__ r_weight,
    const float* __restrict__ k,
    float*       __restrict__ out)
{
    // XCD-chunked swizzle: launched id B runs on XCD B%8 (HW round-robin);
    // give XCD x the contiguous logical range [x*CPX, (x+1)*CPX).
    const int b  = (blockIdx.x % NXCD) * CPX + blockIdx.x / NXCD;

    const int np = b / TOPK;             // n*P2 + p
    const int n  = np / P2;

    const int   idx = r_idx[b];          // routed region index in [0, P2)
    const float w   = r_weight[b];

    const f32x4* __restrict__ src =
        reinterpret_cast<const f32x4*>(k + (size_t)(n * P2 + idx) * WIN);
    f32x4* __restrict__ dst =
        reinterpret_cast<f32x4*>(out + (size_t)b * WIN);

    #pragma unroll
    for (int i = threadIdx.x; i < WINV; i += 256) {
        f32x4 v = src[i] * w;
        __builtin_nontemporal_store(v, &dst[i]);
    }
}

extern "C" void kernel_launch(void* const* d_in, const int* in_sizes, int n_in,
                              void* d_out, int out_size, void* d_ws, size_t ws_size,
                              hipStream_t stream) {
    const int*   r_idx    = (const int*)  d_in[0];
    const float* r_weight = (const float*)d_in[1];
    const float* k        = (const float*)d_in[2];
    float*       out      = (float*)d_out;

    kgather_kernel<<<NWG, 256, 0, stream>>>(r_idx, r_weight, k, out);
}